// Round 1
// baseline (144.599 us; speedup 1.0000x reference)
//
#include <hip/hip_runtime.h>
#include <math.h>

#define S 128
constexpr float TWO_PI_OVER_S = 6.283185307179586f / 128.0f;  // 2*pi/128

// F[b,y,s] = sum_v x[b,y,v] * e^{-2*pi*i*s*v/S}   (1-D row DFT of channel 0)
__global__ void dft_rows(const float* __restrict__ in, float2* __restrict__ F) {
    const int by = blockIdx.x;            // b*128 + y
    const int b  = by >> 7;
    const int y  = by & (S - 1);
    const int s  = threadIdx.x;           // 0..127

    __shared__ float row[S];
    row[s] = in[((b * 2 + 0) * S + y) * S + s];
    __syncthreads();

    float re = 0.f, im = 0.f;
#pragma unroll 4
    for (int v = 0; v < S; ++v) {
        const int k = (s * v) & (S - 1);
        float sn, c;
        __sincosf((float)k * TWO_PI_OVER_S, &sn, &c);
        const float xv = row[v];          // LDS broadcast (all lanes same addr)
        re = fmaf(xv, c, re);
        im = fmaf(xv, -sn, im);
    }
    F[by * S + s] = make_float2(re, im);
}

// imgs[b,s,y,x] = (1/S) * ( Re(F[b,y,s])*cos(2*pi*s*x/S) - Im(F[b,y,s])*sin(2*pi*s*x/S) )
// out layout: out[((b*129 + s)*128 + y)*128 + x]
__global__ void modulate(const float2* __restrict__ F, float* __restrict__ out) {
    const int gid = blockIdx.x * blockDim.x + threadIdx.x;  // 8,388,608 threads
    const int x0  = (gid & 31) * 4;       // 4 contiguous x per thread
    int rem = gid >> 5;
    const int y = rem & (S - 1); rem >>= 7;
    const int s = rem & (S - 1);
    const int b = rem >> 7;

    const float2 f  = F[(b * S + y) * S + s];   // 32-lane broadcast, cached
    const float  re = f.x * (1.0f / S);
    const float  im = f.y * (1.0f / S);

    float4 o;
    float* op = &o.x;
#pragma unroll
    for (int j = 0; j < 4; ++j) {
        const int k = (s * (x0 + j)) & (S - 1);
        float sn, c;
        __sincosf((float)k * TWO_PI_OVER_S, &sn, &c);
        op[j] = re * c - im * sn;
    }
    *reinterpret_cast<float4*>(&out[((b * 129 + s) * S + y) * S + x0]) = o;
}

// out[b,128,y,x] = in[b,1,y,x]
__global__ void copy_others(const float* __restrict__ in, float* __restrict__ out) {
    const int gid = blockIdx.x * blockDim.x + threadIdx.x;  // 65,536 threads
    const int xq  = (gid & 31) * 4;
    int rem = gid >> 5;
    const int y = rem & (S - 1);
    const int b = rem >> 7;
    const float4 v = *reinterpret_cast<const float4*>(&in[((b * 2 + 1) * S + y) * S + xq]);
    *reinterpret_cast<float4*>(&out[((b * 129 + 128) * S + y) * S + xq]) = v;
}

extern "C" void kernel_launch(void* const* d_in, const int* in_sizes, int n_in,
                              void* d_out, int out_size, void* d_ws, size_t ws_size,
                              hipStream_t stream) {
    const float* in  = (const float*)d_in[0];
    float*       out = (float*)d_out;
    float2*      F   = (float2*)d_ws;     // 16*128*128 float2 = 2 MiB

    const int B = 16;

    // 1) row DFTs: one block per (b,y)
    dft_rows<<<B * S, S, 0, stream>>>(in, F);

    // 2) modulation writes: 16*128*128*128 / 4 outputs per thread
    const int total_threads = B * S * S * (S / 4);   // 8,388,608
    modulate<<<total_threads / 256, 256, 0, stream>>>(F, out);

    // 3) passthrough channel
    copy_others<<<(B * S * (S / 4)) / 256, 256, 0, stream>>>(in, out);
}